// Round 7
// baseline (180.916 us; speedup 1.0000x reference)
//
#include <hip/hip_runtime.h>
#include <hip/hip_bf16.h>

#define NQ   14
#define DIM  16384      // 2^14
#define BLK  1024
#define WMUL 0.6324555320336759f  // sqrt(2/5)

typedef float v2f __attribute__((ext_vector_type(2)));

struct C2 { float x, y; };  // build-time only
__device__ inline C2 cmulc(C2 a, C2 b){ return C2{a.x*b.x - a.y*b.y, a.x*b.y + a.y*b.x}; }
__device__ inline C2 caddc(C2 a, C2 b){ return C2{a.x+b.x, a.y+b.y}; }
__device__ inline void mm2(const C2* a, const C2* b, C2* o) {
    o[0] = caddc(cmulc(a[0],b[0]), cmulc(a[1],b[2]));
    o[1] = caddc(cmulc(a[0],b[1]), cmulc(a[1],b[3]));
    o[2] = caddc(cmulc(a[2],b[0]), cmulc(a[3],b[2]));
    o[3] = caddc(cmulc(a[2],b[1]), cmulc(a[3],b[3]));
}
__device__ inline void build_gate(int ty, float t, C2* g) {
    float sn, cs;
    __sincosf(0.5f * t, &sn, &cs);
    if (ty == 0) {        // rx
        g[0] = C2{cs, 0.f}; g[1] = C2{0.f, -sn};
        g[2] = C2{0.f, -sn}; g[3] = C2{cs, 0.f};
    } else if (ty == 1) { // ry
        g[0] = C2{cs, 0.f}; g[1] = C2{-sn, 0.f};
        g[2] = C2{sn, 0.f}; g[3] = C2{cs, 0.f};
    } else {              // rz
        g[0] = C2{cs, -sn}; g[1] = C2{0.f, 0.f};
        g[2] = C2{0.f, 0.f}; g[3] = C2{cs, sn};
    }
}
__device__ const int TYPES[5][3] = {
    {0,1,2},  // XYZ
    {1,2,1},  // YZY
    {2,1,0},  // ZYX
    {0,2,0},  // XZX
    {1,2,1},  // YZY
};

// bank-conflict swizzle; GF(2)-LINEAR: slotf(a|b) = slotf(a)^slotf(b) for disjoint a,b
__device__ inline constexpr uint32_t slotf(uint32_t i){
    return i ^ (((i>>4) ^ (i>>8) ^ (i>>12)) & 15u);
}
template<int B> __device__ inline uint32_t ins0(uint32_t t){
    return ((t & ~((1u<<B)-1u)) << 1) | (t & ((1u<<B)-1u));
}
// deposit t's 10 bits into the complement of window bits B0<B1<B2<B3
template<int B0,int B1,int B2,int B3> __device__ inline uint32_t expand4(uint32_t t){
    return ins0<B3>(ins0<B2>(ins0<B1>(ins0<B0>(t))));
}
template<int B0,int B1,int B2,int B3> __device__ inline constexpr uint32_t rmask4(int r){
    return ((r&1)?(1u<<B0):0u) | ((r&2)?(1u<<B1):0u)
         | ((r&4)?(1u<<B2):0u) | ((r&8)?(1u<<B3):0u);
}

// packed rotation on local bit J over v[16]. g = 8 v2f: {mxx,msw} per coeff,
// mxx=(m.x,m.x), msw=(-m.y,m.y): cmul(m,a) = mxx*a + msw*a.yx
template<int J>
__device__ inline void rot16(v2f* v, const v2f* __restrict__ g){
    const v2f a00=g[0], b00=g[1], a01=g[2], b01=g[3];
    const v2f a10=g[4], b10=g[5], a11=g[6], b11=g[7];
    #pragma unroll
    for (int r = 0; r < 16; ++r){
        if (!(r & (1 << J))) {
            v2f x0 = v[r], x1 = v[r | (1 << J)];
            v2f s0 = x0.yx, s1 = x1.yx;
            v2f y0 = a00*x0 + b00*s0 + a01*x1 + b01*s1;
            v2f y1 = a10*x0 + b10*s0 + a11*x1 + b11*s1;
            v[r] = y0; v[r | (1<<J)] = y1;
        }
    }
}
// CNOT: control local bit C, target local bit T (register renaming, free)
template<int C, int T>
__device__ inline void cnot16(v2f* v){
    #pragma unroll
    for (int r = 0; r < 16; ++r){
        if ((r & (1 << C)) && !(r & (1 << T))) {
            v2f tt = v[r]; v[r] = v[r | (1 << T)]; v[r | (1 << T)] = tt;
        }
    }
}

__global__ __launch_bounds__(BLK) void qsim_kernel(
        const float* __restrict__ xr, const float* __restrict__ xi,
        const float* __restrict__ w, float* __restrict__ out) {
    __shared__ v2f s[DIM];            // 128 KiB statevector (swizzled layout)
    __shared__ v2f gmp[5 * NQ * 8];   // 70 gates, packed-friendly form (4.4 KiB)
    __shared__ float red[BLK / 64];

    const int b   = blockIdx.x;
    const uint32_t tid = threadIdx.x;

    // ---- build fused gate matrices (threads 0..69), store packed form ----
    if (tid < 5 * NQ) {
        const int li = tid / NQ, q = tid % NQ;
        C2 M[4], G[4], T[4];
        #pragma unroll
        for (int j = 0; j < 3; ++j) {
            float t = w[3 * NQ * li + 3 * q + j] * WMUL;
            build_gate(TYPES[li][j], t, G);
            if (j == 0) { M[0]=G[0]; M[1]=G[1]; M[2]=G[2]; M[3]=G[3]; }
            else { mm2(G, M, T); M[0]=T[0]; M[1]=T[1]; M[2]=T[2]; M[3]=T[3]; }
        }
        #pragma unroll
        for (int k = 0; k < 4; ++k) {
            gmp[tid * 8 + k * 2 + 0] = v2f{ M[k].x, M[k].x};
            gmp[tid * 8 + k * 2 + 1] = v2f{-M[k].y, M[k].y};
        }
    }
    __syncthreads();

    const float* xrb = xr + (size_t)b * DIM;
    const float* xib = xi + (size_t)b * DIM;

    // qubit q <-> bit (13-q).
    #define GMP(li, q) (&gmp[((li) * NQ + (q)) * 8])

    // One pass: single v[16] (32 VGPRs), whole state in one sweep.
    #define PASS(B0, B1, B2, B3, ...)                                              \
        {                                                                          \
            const uint32_t sb = slotf(expand4<B0,B1,B2,B3>(tid));                  \
            v2f v[16];                                                             \
            _Pragma("unroll")                                                      \
            for (int r = 0; r < 16; ++r)                                           \
                v[r] = s[sb ^ slotf(rmask4<B0,B1,B2,B3>(r))];                      \
            __VA_ARGS__                                                            \
            _Pragma("unroll")                                                      \
            for (int r = 0; r < 16; ++r)                                           \
                s[sb ^ slotf(rmask4<B0,B1,B2,B3>(r))] = v[r];                      \
        }                                                                          \
        __syncthreads();

    // ---- layers 0..2: 5 windows each (rot(li) + ring CNOTs chained) ----
    #pragma unroll 1
    for (int li = 0; li < 3; ++li) {
        // P1 bits{10..13}: L3=b13(q0), L2=b12(q1), L1=b11(q2), L0=b10(q3)
        {
            v2f v[16];
            if (li == 0) {
                #pragma unroll
                for (int r = 0; r < 16; ++r) {
                    uint32_t i = tid | ((uint32_t)r << 10);   // expand4<10..13>(tid)=tid
                    v[r] = v2f{xrb[i], xib[i]};
                }
            } else {
                const uint32_t sb = slotf(expand4<10,11,12,13>(tid));
                #pragma unroll
                for (int r = 0; r < 16; ++r)
                    v[r] = s[sb ^ slotf(rmask4<10,11,12,13>(r))];
            }
            rot16<3>(v, GMP(li,0)); rot16<2>(v, GMP(li,1));
            rot16<1>(v, GMP(li,2)); rot16<0>(v, GMP(li,3));
            cnot16<3,2>(v); cnot16<2,1>(v); cnot16<1,0>(v);   // (0,1),(1,2),(2,3)
            const uint32_t sb = slotf(expand4<10,11,12,13>(tid));
            #pragma unroll
            for (int r = 0; r < 16; ++r)
                s[sb ^ slotf(rmask4<10,11,12,13>(r))] = v[r];
        }
        __syncthreads();

        // P2 bits{7..10}: L3=b10(q3), L2=b9(q4), L1=b8(q5), L0=b7(q6)
        PASS(7,8,9,10, rot16<2>(v, GMP(li,4)); rot16<1>(v, GMP(li,5)); rot16<0>(v, GMP(li,6));
                       cnot16<3,2>(v); cnot16<2,1>(v); cnot16<1,0>(v);)
        // P3 bits{4..7}: q6,q7,q8,q9
        PASS(4,5,6,7,  rot16<2>(v, GMP(li,7)); rot16<1>(v, GMP(li,8)); rot16<0>(v, GMP(li,9));
                       cnot16<3,2>(v); cnot16<2,1>(v); cnot16<1,0>(v);)
        // P4 bits{1..4}: q9,q10,q11,q12
        PASS(1,2,3,4,  rot16<2>(v, GMP(li,10)); rot16<1>(v, GMP(li,11)); rot16<0>(v, GMP(li,12));
                       cnot16<3,2>(v); cnot16<2,1>(v); cnot16<1,0>(v);)
        // P5 bits{0,1,2,13}: L0=b0(q13), L1=b1(q12), L2=b2(idle), L3=b13(q0)
        PASS(0,1,2,13, rot16<0>(v, GMP(li,13)); cnot16<1,0>(v); cnot16<0,3>(v);)
    }

    // ---- layer 3 ring windows with layer-4 rotations folded in where both
    //      ring CNOTs touching the qubit are complete ----
    PASS(10,11,12,13, rot16<3>(v, GMP(3,0));  rot16<2>(v, GMP(3,1));
                      rot16<1>(v, GMP(3,2));  rot16<0>(v, GMP(3,3));
                      cnot16<3,2>(v); cnot16<2,1>(v); cnot16<1,0>(v);
                      rot16<2>(v, GMP(4,1));  rot16<1>(v, GMP(4,2));)
    PASS(7,8,9,10,    rot16<2>(v, GMP(3,4));  rot16<1>(v, GMP(3,5));  rot16<0>(v, GMP(3,6));
                      cnot16<3,2>(v); cnot16<2,1>(v); cnot16<1,0>(v);
                      rot16<3>(v, GMP(4,3));  rot16<2>(v, GMP(4,4));  rot16<1>(v, GMP(4,5));)
    PASS(4,5,6,7,     rot16<2>(v, GMP(3,7));  rot16<1>(v, GMP(3,8));  rot16<0>(v, GMP(3,9));
                      cnot16<3,2>(v); cnot16<2,1>(v); cnot16<1,0>(v);
                      rot16<3>(v, GMP(4,6));  rot16<2>(v, GMP(4,7));  rot16<1>(v, GMP(4,8));)
    PASS(1,2,3,4,     rot16<2>(v, GMP(3,10)); rot16<1>(v, GMP(3,11)); rot16<0>(v, GMP(3,12));
                      cnot16<3,2>(v); cnot16<2,1>(v); cnot16<1,0>(v);
                      rot16<3>(v, GMP(4,9));  rot16<2>(v, GMP(4,10)); rot16<1>(v, GMP(4,11));)

    // final window bits{0,1,2,13}: rot3(q13); CNOT(12,13); CNOT(13,0);
    // rot4(q12,q13,q0); fused <Z_0>, no scatter. sign: b13 = L3 = (r&8).
    float local = 0.f;
    {
        const uint32_t sb = slotf(expand4<0,1,2,13>(tid));
        v2f v[16];
        #pragma unroll
        for (int r = 0; r < 16; ++r)
            v[r] = s[sb ^ slotf(rmask4<0,1,2,13>(r))];
        rot16<0>(v, GMP(3,13));
        cnot16<1,0>(v); cnot16<0,3>(v);
        rot16<1>(v, GMP(4,12)); rot16<0>(v, GMP(4,13)); rot16<3>(v, GMP(4,0));
        #pragma unroll
        for (int r = 0; r < 16; ++r) {
            v2f p = v[r] * v[r];
            float m = p.x + p.y;
            local += (r & 8) ? -m : m;
        }
    }

    #pragma unroll
    for (int off = 32; off > 0; off >>= 1) local += __shfl_down(local, off);
    const int lane = tid & 63, wid = tid >> 6;
    if (lane == 0) red[wid] = local;
    __syncthreads();
    if (tid == 0) {
        float t = 0.f;
        #pragma unroll
        for (int k = 0; k < BLK / 64; ++k) t += red[k];
        out[b] = t;
    }
}

extern "C" void kernel_launch(void* const* d_in, const int* in_sizes, int n_in,
                              void* d_out, int out_size, void* d_ws, size_t ws_size,
                              hipStream_t stream) {
    const float* xr = (const float*)d_in[0];
    const float* xi = (const float*)d_in[1];
    const float* w  = (const float*)d_in[2];
    float* out = (float*)d_out;
    const int B = out_size;  // 512
    qsim_kernel<<<B, BLK, 0, stream>>>(xr, xi, w, out);
}

// Round 8
// 138.023 us; speedup vs baseline: 1.3108x; 1.3108x over previous
//
#include <hip/hip_runtime.h>
#include <hip/hip_bf16.h>

#define NQ   14
#define DIM  16384      // 2^14
#define BLK  1024
#define WMUL 0.6324555320336759f  // sqrt(2/5)

typedef float v2f __attribute__((ext_vector_type(2)));

struct C2 { float x, y; };  // build-time only
__device__ inline C2 cmulc(C2 a, C2 b){ return C2{a.x*b.x - a.y*b.y, a.x*b.y + a.y*b.x}; }
__device__ inline C2 caddc(C2 a, C2 b){ return C2{a.x+b.x, a.y+b.y}; }
__device__ inline void mm2(const C2* a, const C2* b, C2* o) {
    o[0] = caddc(cmulc(a[0],b[0]), cmulc(a[1],b[2]));
    o[1] = caddc(cmulc(a[0],b[1]), cmulc(a[1],b[3]));
    o[2] = caddc(cmulc(a[2],b[0]), cmulc(a[3],b[2]));
    o[3] = caddc(cmulc(a[2],b[1]), cmulc(a[3],b[3]));
}
__device__ inline void build_gate(int ty, float t, C2* g) {
    float sn, cs;
    __sincosf(0.5f * t, &sn, &cs);
    if (ty == 0) {        // rx
        g[0] = C2{cs, 0.f}; g[1] = C2{0.f, -sn};
        g[2] = C2{0.f, -sn}; g[3] = C2{cs, 0.f};
    } else if (ty == 1) { // ry
        g[0] = C2{cs, 0.f}; g[1] = C2{-sn, 0.f};
        g[2] = C2{sn, 0.f}; g[3] = C2{cs, 0.f};
    } else {              // rz
        g[0] = C2{cs, -sn}; g[1] = C2{0.f, 0.f};
        g[2] = C2{0.f, 0.f}; g[3] = C2{cs, sn};
    }
}
__device__ const int TYPES[5][3] = {
    {0,1,2},  // XYZ
    {1,2,1},  // YZY
    {2,1,0},  // ZYX
    {0,2,0},  // XZX
    {1,2,1},  // YZY
};

// bank-conflict swizzle; GF(2)-LINEAR: slotf(a|b) = slotf(a)^slotf(b) for disjoint a,b
__device__ inline constexpr uint32_t slotf(uint32_t i){
    return i ^ (((i>>4) ^ (i>>8) ^ (i>>12)) & 15u);
}
template<int B> __device__ inline uint32_t ins0(uint32_t t){
    return ((t & ~((1u<<B)-1u)) << 1) | (t & ((1u<<B)-1u));
}
template<int B0,int B1,int B2> __device__ inline uint32_t expand3(uint32_t t){
    return ins0<B2>(ins0<B1>(ins0<B0>(t)));
}
template<int B0,int B1,int B2> __device__ inline constexpr uint32_t rmask3(int r){
    return ((r&1)?(1u<<B0):0u) | ((r&2)?(1u<<B1):0u) | ((r&4)?(1u<<B2):0u);
}

// Packed rotation on local bit J. g = 8 v2f: {mxx,msw} per coeff (00,01,10,11),
// mxx=(m.x,m.x), msw=(-m.y,m.y): cmul(m,a) = mxx*a + msw*swz(a).
// Inline asm guarantees VOP3P: swz folds into op_sel (D.lo<-S1.hi, D.hi<-S1.lo),
// so each pair-output is exactly 1 v_pk_mul_f32 + 3 v_pk_fma_f32.
template<int J>
__device__ inline void rot8(v2f* v, const v2f* __restrict__ g){
    const v2f a00=g[0], b00=g[1], a01=g[2], b01=g[3];
    const v2f a10=g[4], b10=g[5], a11=g[6], b11=g[7];
    #pragma unroll
    for (int r = 0; r < 8; ++r){
        if (!(r & (1 << J))) {
            v2f x0 = v[r], x1 = v[r | (1 << J)];
            v2f y0, y1;
            asm("v_pk_mul_f32 %0, %1, %2" : "=v"(y0) : "v"(a00), "v"(x0));
            asm("v_pk_fma_f32 %0, %1, %2, %0 op_sel:[0,1,0] op_sel_hi:[1,0,1]"
                : "+v"(y0) : "v"(b00), "v"(x0));
            asm("v_pk_fma_f32 %0, %1, %2, %0"
                : "+v"(y0) : "v"(a01), "v"(x1));
            asm("v_pk_fma_f32 %0, %1, %2, %0 op_sel:[0,1,0] op_sel_hi:[1,0,1]"
                : "+v"(y0) : "v"(b01), "v"(x1));
            asm("v_pk_mul_f32 %0, %1, %2" : "=v"(y1) : "v"(a10), "v"(x0));
            asm("v_pk_fma_f32 %0, %1, %2, %0 op_sel:[0,1,0] op_sel_hi:[1,0,1]"
                : "+v"(y1) : "v"(b10), "v"(x0));
            asm("v_pk_fma_f32 %0, %1, %2, %0"
                : "+v"(y1) : "v"(a11), "v"(x1));
            asm("v_pk_fma_f32 %0, %1, %2, %0 op_sel:[0,1,0] op_sel_hi:[1,0,1]"
                : "+v"(y1) : "v"(b11), "v"(x1));
            v[r] = y0; v[r | (1<<J)] = y1;
        }
    }
}
// CNOT: control local bit C, target local bit T (register renaming, ~free)
template<int C, int T>
__device__ inline void cnot8(v2f* v){
    #pragma unroll
    for (int r = 0; r < 8; ++r){
        if ((r & (1 << C)) && !(r & (1 << T))) {
            v2f tt = v[r]; v[r] = v[r | (1 << T)]; v[r | (1 << T)] = tt;
        }
    }
}

__global__ __launch_bounds__(BLK) void qsim_kernel(
        const float* __restrict__ xr, const float* __restrict__ xi,
        const float* __restrict__ w, float* __restrict__ out) {
    __shared__ v2f s[DIM];            // 128 KiB statevector (swizzled layout)
    __shared__ v2f gmp[5 * NQ * 8];   // 70 gates, packed-friendly form (4.4 KiB)
    __shared__ float red[BLK / 64];

    const int b   = blockIdx.x;
    const uint32_t tid = threadIdx.x;

    // ---- build fused gate matrices (threads 0..69), store packed form ----
    if (tid < 5 * NQ) {
        const int li = tid / NQ, q = tid % NQ;
        C2 M[4], G[4], T[4];
        #pragma unroll
        for (int j = 0; j < 3; ++j) {
            float t = w[3 * NQ * li + 3 * q + j] * WMUL;
            build_gate(TYPES[li][j], t, G);
            if (j == 0) { M[0]=G[0]; M[1]=G[1]; M[2]=G[2]; M[3]=G[3]; }
            else { mm2(G, M, T); M[0]=T[0]; M[1]=T[1]; M[2]=T[2]; M[3]=T[3]; }
        }
        #pragma unroll
        for (int k = 0; k < 4; ++k) {
            gmp[tid * 8 + k * 2 + 0] = v2f{ M[k].x, M[k].x};
            gmp[tid * 8 + k * 2 + 1] = v2f{-M[k].y, M[k].y};
        }
    }
    __syncthreads();

    const float* xrb = xr + (size_t)b * DIM;
    const float* xib = xi + (size_t)b * DIM;

    // qubit q <-> bit (13-q).
    #define GMP(li, q) (&gmp[((li) * NQ + (q)) * 8])

    // One pass: 2 sequential slabs (live state = v2f v[8] = 16 VGPRs).
    #define PASS(B0, B1, B2, ...)                                                  \
        _Pragma("unroll 1")                                                        \
        for (uint32_t sl = 0; sl < 2; ++sl) {                                      \
            const uint32_t t  = tid + sl * BLK;                                    \
            const uint32_t sb = slotf(expand3<B0,B1,B2>(t));                       \
            v2f v[8];                                                              \
            _Pragma("unroll")                                                      \
            for (int r = 0; r < 8; ++r)                                            \
                v[r] = s[sb ^ slotf(rmask3<B0,B1,B2>(r))];                         \
            __VA_ARGS__                                                            \
            _Pragma("unroll")                                                      \
            for (int r = 0; r < 8; ++r)                                            \
                s[sb ^ slotf(rmask3<B0,B1,B2>(r))] = v[r];                         \
        }                                                                          \
        __syncthreads();

    // ---- layers 0..2: 7 windows each (rot(li) + ring CNOTs chained) ----
    #pragma unroll 1
    for (int li = 0; li < 3; ++li) {
        // W1 bits{11,12,13}: L2=q0, L1=q1, L0=q2
        #pragma unroll 1
        for (uint32_t sl = 0; sl < 2; ++sl) {
            const uint32_t t = tid + sl * BLK;
            v2f v[8];
            if (li == 0) {
                #pragma unroll
                for (int r = 0; r < 8; ++r) {
                    uint32_t i = t | ((uint32_t)r << 11);   // expand3<11,12,13>(t)=t
                    v[r] = v2f{xrb[i], xib[i]};
                }
            } else {
                const uint32_t sb = slotf(expand3<11,12,13>(t));
                #pragma unroll
                for (int r = 0; r < 8; ++r)
                    v[r] = s[sb ^ slotf(rmask3<11,12,13>(r))];
            }
            rot8<2>(v, GMP(li,0)); rot8<1>(v, GMP(li,1)); rot8<0>(v, GMP(li,2));
            cnot8<2,1>(v); cnot8<1,0>(v);
            const uint32_t sb = slotf(expand3<11,12,13>(t));
            #pragma unroll
            for (int r = 0; r < 8; ++r)
                s[sb ^ slotf(rmask3<11,12,13>(r))] = v[r];
        }
        __syncthreads();

        PASS(9,10,11, rot8<1>(v, GMP(li,3));  rot8<0>(v, GMP(li,4));  cnot8<2,1>(v); cnot8<1,0>(v);)
        PASS(7,8,9,   rot8<1>(v, GMP(li,5));  rot8<0>(v, GMP(li,6));  cnot8<2,1>(v); cnot8<1,0>(v);)
        PASS(5,6,7,   rot8<1>(v, GMP(li,7));  rot8<0>(v, GMP(li,8));  cnot8<2,1>(v); cnot8<1,0>(v);)
        PASS(3,4,5,   rot8<1>(v, GMP(li,9));  rot8<0>(v, GMP(li,10)); cnot8<2,1>(v); cnot8<1,0>(v);)
        PASS(1,2,3,   rot8<1>(v, GMP(li,11)); rot8<0>(v, GMP(li,12)); cnot8<2,1>(v); cnot8<1,0>(v);)
        // W7 bits{0,1,13}: L0=q13, L1=q12, L2=q0
        PASS(0,1,13,  rot8<0>(v, GMP(li,13)); cnot8<1,0>(v); cnot8<0,2>(v);)
    }

    // ---- layer 3 ring windows, with layer-4 rotations folded in where both
    //      ring CNOTs touching the qubit are done (later ring gates commute) ----
    PASS(11,12,13, rot8<2>(v, GMP(3,0));  rot8<1>(v, GMP(3,1));  rot8<0>(v, GMP(3,2));
                   cnot8<2,1>(v); cnot8<1,0>(v);
                   rot8<1>(v, GMP(4,1));)
    PASS(9,10,11,  rot8<1>(v, GMP(3,3));  rot8<0>(v, GMP(3,4));
                   cnot8<2,1>(v); cnot8<1,0>(v);
                   rot8<2>(v, GMP(4,2));  rot8<1>(v, GMP(4,3));)
    PASS(7,8,9,    rot8<1>(v, GMP(3,5));  rot8<0>(v, GMP(3,6));
                   cnot8<2,1>(v); cnot8<1,0>(v);
                   rot8<2>(v, GMP(4,4));  rot8<1>(v, GMP(4,5));)
    PASS(5,6,7,    rot8<1>(v, GMP(3,7));  rot8<0>(v, GMP(3,8));
                   cnot8<2,1>(v); cnot8<1,0>(v);
                   rot8<2>(v, GMP(4,6));  rot8<1>(v, GMP(4,7));)
    PASS(3,4,5,    rot8<1>(v, GMP(3,9));  rot8<0>(v, GMP(3,10));
                   cnot8<2,1>(v); cnot8<1,0>(v);
                   rot8<2>(v, GMP(4,8));  rot8<1>(v, GMP(4,9));)
    PASS(1,2,3,    rot8<1>(v, GMP(3,11)); rot8<0>(v, GMP(3,12));
                   cnot8<2,1>(v); cnot8<1,0>(v);
                   rot8<2>(v, GMP(4,10)); rot8<1>(v, GMP(4,11));)

    // final window bits{0,1,13}: L0=q13, L1=q12, L2=q0.
    // rot3(q13); CNOT(12,13); CNOT(13,0); rot4(q12,q13,q0); fused <Z_0>, no scatter.
    // sign: idx bit13 (q0) = local bit 2 = (r&4).
    float local = 0.f;
    #pragma unroll 1
    for (uint32_t sl = 0; sl < 2; ++sl) {
        const uint32_t t  = tid + sl * BLK;
        const uint32_t sb = slotf(expand3<0,1,13>(t));
        v2f v[8];
        #pragma unroll
        for (int r = 0; r < 8; ++r)
            v[r] = s[sb ^ slotf(rmask3<0,1,13>(r))];
        rot8<0>(v, GMP(3,13));
        cnot8<1,0>(v); cnot8<0,2>(v);
        rot8<1>(v, GMP(4,12)); rot8<0>(v, GMP(4,13)); rot8<2>(v, GMP(4,0));
        #pragma unroll
        for (int r = 0; r < 8; ++r) {
            v2f p = v[r] * v[r];
            float m = p.x + p.y;
            local += (r & 4) ? -m : m;
        }
    }

    #pragma unroll
    for (int off = 32; off > 0; off >>= 1) local += __shfl_down(local, off);
    const int lane = tid & 63, wid = tid >> 6;
    if (lane == 0) red[wid] = local;
    __syncthreads();
    if (tid == 0) {
        float t = 0.f;
        #pragma unroll
        for (int k = 0; k < BLK / 64; ++k) t += red[k];
        out[b] = t;
    }
}

extern "C" void kernel_launch(void* const* d_in, const int* in_sizes, int n_in,
                              void* d_out, int out_size, void* d_ws, size_t ws_size,
                              hipStream_t stream) {
    const float* xr = (const float*)d_in[0];
    const float* xi = (const float*)d_in[1];
    const float* w  = (const float*)d_in[2];
    float* out = (float*)d_out;
    const int B = out_size;  // 512
    qsim_kernel<<<B, BLK, 0, stream>>>(xr, xi, w, out);
}